// Round 5
// baseline (876.034 us; speedup 1.0000x reference)
//
#include <hip/hip_runtime.h>
#include <hip/hip_bf16.h>
#include <math.h>

#define NROWS 25600
#define SEQL  25
#define EPSV  1e-6f

typedef __hip_bfloat16 bf16;
typedef __attribute__((ext_vector_type(4))) float f32x4;
typedef __attribute__((ext_vector_type(8))) short bf16x8;
typedef __attribute__((ext_vector_type(4))) short s16x4;
typedef unsigned int u32;

#define GLD16(gp_, lp_) __builtin_amdgcn_global_load_lds( \
    (const __attribute__((address_space(1))) u32*)(gp_), \
    (__attribute__((address_space(3))) u32*)(lp_), 16, 0, 0)

__device__ __forceinline__ float b2f(short s) {
  return __uint_as_float(((u32)(unsigned short)s) << 16);
}
__device__ __forceinline__ short f2b(float f) {
  __hip_bfloat16 h = __float2bfloat16(f);
  return *reinterpret_cast<short*>(&h);
}

// ---------------- Cl(3,0) geometric product (fp32) --------------------------
__device__ __forceinline__ void gprod(const float* a, const float* b, float* r) {
  const int M[8] = {0,1,2,4,3,5,6,7};
  const int P[8] = {0,1,2,4,3,5,6,7};
#pragma unroll
  for (int i = 0; i < 8; ++i) {
    const int ma = M[i];
#pragma unroll
    for (int k = 0; k < 8; ++k) {
      const int mb = M[k];
      int par = 0;
      for (int t = ma >> 1; t; t >>= 1) par += __popc(t & mb);
      const float s = (par & 1) ? -1.f : 1.f;
      r[P[ma ^ mb]] += s * a[i] * b[k];
    }
  }
}

// ---------------- plane-looped MFMA GEMM ------------------------------------
// A planar [8][NROWS][KS] bf16 (K cols = first KT of the row)
// W [4 grades][ONW][KT] bf16 ; bias [ONW] ; optional invnm per row
// Each block: 128-row x 128-col tile, loops 4 planes (z in {0,1} picks half).
// W fragments loaded straight from global (L2-hot) into registers.
// FINAL: epilogue writes fp32 interleaved out = acc + ln3a*nm4inv*X3.
struct GemmArgs {
  const bf16* A; const bf16* W; const float* bias; const float* invnm;
  bf16* Y0; bf16* Y1; bf16* Y2; bf16* Y3;
  int yc0, yc1, yc2, yc3;
  int ONW; int ONS;
  const bf16* X3; const float* ln3a; const float* nm4inv; float* outf;
};

template<int KT, int KS, bool FINAL>
__global__ __launch_bounds__(256) void gemm2_kernel(GemmArgs P)
{
  __shared__ __align__(16) short As[128 * 128];
  const int tid  = threadIdx.x;
  const int lane = tid & 63;
  const int wid  = tid >> 6;
  const int z    = blockIdx.z;   // 0..1 -> planes z*4 .. z*4+3
  const int by   = blockIdx.y;
  const size_t n0 = (size_t)blockIdx.x * 128;
  const int wm = (wid & 1) * 64;
  const int wn = (wid >> 1) * 64;
  const int lg  = lane >> 4;
  const int c8  = lane & 15;
  const int l15 = lane & 15;
  constexpr int NC = KT / 128;

  bf16* Yb = nullptr; int yc = 0;
  if (!FINAL) {
    Yb = (by == 0) ? P.Y0 : (by == 1) ? P.Y1 : (by == 2) ? P.Y2 : P.Y3;
    yc = (by == 0) ? P.yc0 : (by == 1) ? P.yc1 : (by == 2) ? P.yc2 : P.yc3;
  }

  for (int pi = 0; pi < 4; ++pi) {
    const int p = z * 4 + pi;
    const int g = (p == 0) ? 0 : ((p < 4) ? 1 : ((p < 7) ? 2 : 3));
    const bf16* Ab = P.A + (size_t)p * NROWS * KS + n0 * KS;

    f32x4 acc[4][4];
#pragma unroll
    for (int i = 0; i < 4; ++i)
#pragma unroll
      for (int j = 0; j < 4; ++j) acc[i][j] = (f32x4){0.f, 0.f, 0.f, 0.f};

    for (int kc = 0; kc < NC; ++kc) {
      // stage A tile (swizzled source col, linear LDS dest)
#pragma unroll
      for (int j = 0; j < 8; ++j) {
        const int row = wid * 32 + j * 4 + lg;
        const int sw = (c8 ^ (row & 7)) * 8;
        GLD16(Ab + (size_t)row * KS + kc * 128 + sw, &As[wid * 4096 + j * 512]);
      }
      // W fragments direct from global (drained by the barrier's vmcnt(0))
      bf16x8 wf[4][4];
#pragma unroll
      for (int ni = 0; ni < 4; ++ni)
#pragma unroll
        for (int ks = 0; ks < 4; ++ks)
          wf[ni][ks] = *(const bf16x8*)(P.W +
              ((size_t)g * P.ONW + by * 128 + wn + ni * 16 + l15) * KT +
              kc * 128 + ks * 32 + lg * 8);
      __syncthreads();
#pragma unroll
      for (int ks = 0; ks < 4; ++ks) {
        bf16x8 af[4];
#pragma unroll
        for (int mi = 0; mi < 4; ++mi) {
          const int rA = wm + mi * 16 + l15;
          af[mi] = *(const bf16x8*)&As[rA * 128 + (((ks * 4 + lg) ^ (rA & 7)) * 8)];
        }
#pragma unroll
        for (int mi = 0; mi < 4; ++mi)
#pragma unroll
          for (int ni = 0; ni < 4; ++ni)
            acc[mi][ni] = __builtin_amdgcn_mfma_f32_16x16x32_bf16(af[mi], wf[ni][ks], acc[mi][ni], 0, 0, 0);
      }
      __syncthreads();
    }

    const int cr = (lane >> 4) * 4;
    const int cc = lane & 15;
    if (!FINAL) {
      bf16* Yp = Yb + (size_t)p * NROWS * P.ONS + yc;
#pragma unroll
      for (int mi = 0; mi < 4; ++mi) {
#pragma unroll
        for (int j = 0; j < 4; ++j) {
          const size_t n = n0 + wm + mi * 16 + cr + j;
          const float sc = P.invnm ? P.invnm[n] : 1.f;
#pragma unroll
          for (int ni = 0; ni < 4; ++ni) {
            const int cl = wn + ni * 16 + cc;
            float v = acc[mi][ni][j] * sc;
            if (p == 0) v += P.bias[by * 128 + cl];
            Yp[n * P.ONS + cl] = __float2bfloat16(v);
          }
        }
      }
    } else {
#pragma unroll
      for (int mi = 0; mi < 4; ++mi) {
#pragma unroll
        for (int j = 0; j < 4; ++j) {
          const size_t n = n0 + wm + mi * 16 + cr + j;
          const float s3 = P.nm4inv[n];
#pragma unroll
          for (int ni = 0; ni < 4; ++ni) {
            const int cl = wn + ni * 16 + cc;
            float v = acc[mi][ni][j];
            if (p == 0) v += P.bias[cl];
            const float x3v = __bfloat162float(P.X3[(size_t)p * NROWS * 128 + n * 128 + cl]);
            P.outf[(n * 128 + cl) * 8 + p] = v + P.ln3a[cl] * s3 * x3v;
          }
        }
      }
    }
  }
}

// ---------------- weight prep: pack into combined planar bf16 weights -------
__global__ __launch_bounds__(256) void wprep_all_kernel(
    const float* wq, const float* wk, const float* wv, const float* wo,
    const float* gw1, const float* gw2, const float* gw3,
    const float* mw1, const float* mw2,
    const float* ln1, const float* ln2, const float* ln3,
    bf16* WQKV, bf16* WO, bf16* WG12, bf16* WG3, bf16* WM1, bf16* WM2)
{
  const int gid = blockIdx.x * 256 + threadIdx.x;
  const float* w; const float* ln; bf16* out; int K; int idx; int planeSz; int rowOfs;
  if      (gid <  16384) { w=wq;  ln=ln1;     out=WQKV; K=128; idx=gid;        planeSz=49152; rowOfs=0;   }
  else if (gid <  32768) { w=wk;  ln=ln1;     out=WQKV; K=128; idx=gid-16384;  planeSz=49152; rowOfs=128; }
  else if (gid <  49152) { w=wv;  ln=ln1;     out=WQKV; K=128; idx=gid-32768;  planeSz=49152; rowOfs=256; }
  else if (gid <  65536) { w=wo;  ln=nullptr; out=WO;   K=128; idx=gid-49152;  planeSz=16384; rowOfs=0;   }
  else if (gid <  98304) { w=gw1; ln=ln2;     out=WG12; K=128; idx=gid-65536;  planeSz=65536; rowOfs=0;   }
  else if (gid < 131072) { w=gw2; ln=ln2;     out=WG12; K=128; idx=gid-98304;  planeSz=65536; rowOfs=256; }
  else if (gid < 163840) { w=gw3; ln=nullptr; out=WG3;  K=256; idx=gid-131072; planeSz=32768; rowOfs=0;   }
  else if (gid < 196608) { w=mw1; ln=ln3;     out=WM1;  K=128; idx=gid-163840; planeSz=32768; rowOfs=0;   }
  else                   { w=mw2; ln=nullptr; out=WM2;  K=256; idx=gid-196608; planeSz=32768; rowOfs=0;   }
  const int k = idx % K;
  const float s = ln ? ln[k] : 1.f;
  const float4 wv4 = *(const float4*)(w + (size_t)idx * 4);
  bf16* dst = out + (size_t)rowOfs * K + idx;
  dst[0 * planeSz] = __float2bfloat16(wv4.x * s);
  dst[1 * planeSz] = __float2bfloat16(wv4.y * s);
  dst[2 * planeSz] = __float2bfloat16(wv4.z * s);
  dst[3 * planeSz] = __float2bfloat16(wv4.w * s);
}

// ---------------- combined bias buffers -------------------------------------
__global__ __launch_bounds__(256) void bias_prep_kernel(
    const float* bq, const float* bk, const float* bv,
    const float* gb1, const float* gb2,
    float* BQKV, float* BG12)
{
  const int t = blockIdx.x * 256 + threadIdx.x;
  if      (t < 128) BQKV[t] = bq[t];
  else if (t < 256) BQKV[t] = bk[t - 128];
  else if (t < 384) BQKV[t] = bv[t - 256];
  else if (t < 640) BG12[t - 384] = gb1[t - 384];
  else if (t < 896) BG12[t - 384] = gb2[t - 640];
}

// ---------------- repack: src f32 [n][128][8] -> Xp bf16 planar + 1/nm1 -----
__global__ __launch_bounds__(256) void repack_kernel(
    const float* __restrict__ src, bf16* __restrict__ Xp, float* __restrict__ nminv)
{
  const int tid = threadIdx.x;
  const size_t base = ((size_t)blockIdx.x * 256 + tid) * 4;
  const size_t P = (size_t)NROWS * 128;
  float v[4][8];
  const float4* sp = (const float4*)(src + base * 8);
  float part = 0.f;
#pragma unroll
  for (int e = 0; e < 4; ++e) {
    const float4 a = sp[e * 2], b = sp[e * 2 + 1];
    v[e][0]=a.x; v[e][1]=a.y; v[e][2]=a.z; v[e][3]=a.w;
    v[e][4]=b.x; v[e][5]=b.y; v[e][6]=b.z; v[e][7]=b.w;
    float ss = 0.f;
#pragma unroll
    for (int p = 0; p < 8; ++p) ss += v[e][p] * v[e][p];
    part += sqrtf(ss);
  }
#pragma unroll
  for (int p = 0; p < 8; ++p) {
    s16x4 o;
#pragma unroll
    for (int e = 0; e < 4; ++e) o[e] = f2b(v[e][p]);
    *(s16x4*)(Xp + p * P + base) = o;
  }
#pragma unroll
  for (int off = 1; off < 32; off <<= 1) part += __shfl_xor(part, off);
  if ((tid & 31) == 0) nminv[base >> 7] = 1.f / (part / 128.f + EPSV);
}

// ---------------- attention: 1 wave per (b,h); MFMA QK^T, in-reg softmax ----
__global__ __launch_bounds__(256) void attn_kernel(
    bf16* __restrict__ Q, const bf16* __restrict__ K, const bf16* __restrict__ V)
{
  __shared__ float Pld[4][32 * 36];
  const int tid  = threadIdx.x;
  const int lane = tid & 63;
  const int wid  = tid >> 6;
  const int job  = blockIdx.x * 4 + wid;
  const int b    = job >> 3;
  const int h    = job & 7;
  const size_t PS = (size_t)NROWS * 128;
  const int rowbase = b * SEQL;
  const int l15 = lane & 15;
  const int lg  = lane >> 4;

  f32x4 acc[2][2];
#pragma unroll
  for (int si = 0; si < 2; ++si)
#pragma unroll
    for (int ti = 0; ti < 2; ++ti) acc[si][ti] = (f32x4){0.f,0.f,0.f,0.f};

#pragma unroll
  for (int ks = 0; ks < 4; ++ks) {
    const int f = ks * 32 + lg * 8;
    const int p = f >> 4, d = f & 15;
    bf16x8 aq[2], bk[2];
#pragma unroll
    for (int si = 0; si < 2; ++si) {
      int s = si * 16 + l15; if (s > 24) s = 24;
      aq[si] = *(const bf16x8*)(Q + (size_t)p * PS + (size_t)(rowbase + s) * 128 + h * 16 + d);
    }
#pragma unroll
    for (int ti = 0; ti < 2; ++ti) {
      int t = ti * 16 + l15; if (t > 24) t = 24;
      bk[ti] = *(const bf16x8*)(K + (size_t)p * PS + (size_t)(rowbase + t) * 128 + h * 16 + d);
    }
#pragma unroll
    for (int si = 0; si < 2; ++si)
#pragma unroll
      for (int ti = 0; ti < 2; ++ti)
        acc[si][ti] = __builtin_amdgcn_mfma_f32_16x16x32_bf16(aq[si], bk[ti], acc[si][ti], 0, 0, 0);
  }

  const float scale = 0.08838834764831845f;
  float pv[2][2][4];
#pragma unroll
  for (int si = 0; si < 2; ++si)
#pragma unroll
    for (int ti = 0; ti < 2; ++ti)
#pragma unroll
      for (int r = 0; r < 4; ++r) {
        float v = acc[si][ti][r] * scale;
        if (ti * 16 + l15 > 24) v = -1e30f;
        pv[si][ti][r] = v;
      }
#pragma unroll
  for (int si = 0; si < 2; ++si)
#pragma unroll
    for (int r = 0; r < 4; ++r) {
      float m = fmaxf(pv[si][0][r], pv[si][1][r]);
#pragma unroll
      for (int off = 1; off < 16; off <<= 1) m = fmaxf(m, __shfl_xor(m, off));
      const float e0 = __expf(pv[si][0][r] - m);
      const float e1 = __expf(pv[si][1][r] - m);
      float sum = e0 + e1;
#pragma unroll
      for (int off = 1; off < 16; off <<= 1) sum += __shfl_xor(sum, off);
      const float inv = 1.f / sum;
      pv[si][0][r] = e0 * inv;
      pv[si][1][r] = e1 * inv;
    }

  float* Pw = &Pld[wid][0];
#pragma unroll
  for (int si = 0; si < 2; ++si)
#pragma unroll
    for (int ti = 0; ti < 2; ++ti)
#pragma unroll
      for (int r = 0; r < 4; ++r)
        Pw[(si * 16 + lg * 4 + r) * 36 + ti * 16 + l15] = pv[si][ti][r];
  __syncthreads();

  const int p2 = lane >> 3;
  const int d2 = (lane & 7) * 2;
  const bf16* vb = V + (size_t)p2 * PS + (size_t)rowbase * 128 + h * 16 + d2;
  float vlo[32], vhi[32];
#pragma unroll
  for (int t = 0; t < SEQL; ++t) {
    const __hip_bfloat162 vv = *(const __hip_bfloat162*)(vb + (size_t)t * 128);
    vlo[t] = __bfloat162float(vv.x);
    vhi[t] = __bfloat162float(vv.y);
  }
#pragma unroll
  for (int t = SEQL; t < 32; ++t) { vlo[t] = 0.f; vhi[t] = 0.f; }

  bf16* ob = Q + (size_t)p2 * PS + (size_t)rowbase * 128 + h * 16 + d2;
  for (int s = 0; s < SEQL; ++s) {
    const float4* pr = reinterpret_cast<const float4*>(&Pld[wid][s * 36]);
    float a0 = 0.f, a1 = 0.f;
#pragma unroll
    for (int t4 = 0; t4 < 8; ++t4) {
      const float4 pq = pr[t4];
      a0 += pq.x * vlo[t4*4+0] + pq.y * vlo[t4*4+1] + pq.z * vlo[t4*4+2] + pq.w * vlo[t4*4+3];
      a1 += pq.x * vhi[t4*4+0] + pq.y * vhi[t4*4+1] + pq.z * vhi[t4*4+2] + pq.w * vhi[t4*4+3];
    }
    __hip_bfloat162 o2;
    o2.x = __float2bfloat16(a0);
    o2.y = __float2bfloat16(a1);
    *(__hip_bfloat162*)(ob + (size_t)s * 128) = o2;
  }
}

// ---------------- xres = src + AO (4-wide) + 1/nm2 --------------------------
__global__ __launch_bounds__(256) void xres_kernel(
    const float* __restrict__ src, const bf16* __restrict__ AO,
    bf16* __restrict__ X, float* __restrict__ nminv)
{
  const int tid = threadIdx.x;
  const size_t base = ((size_t)blockIdx.x * 256 + tid) * 4;
  const size_t P = (size_t)NROWS * 128;
  float v[4][8];
  const float4* sp = (const float4*)(src + base * 8);
#pragma unroll
  for (int e = 0; e < 4; ++e) {
    const float4 a = sp[e * 2], b = sp[e * 2 + 1];
    v[e][0]=a.x; v[e][1]=a.y; v[e][2]=a.z; v[e][3]=a.w;
    v[e][4]=b.x; v[e][5]=b.y; v[e][6]=b.z; v[e][7]=b.w;
  }
  float part = 0.f;
  float ss[4] = {0.f, 0.f, 0.f, 0.f};
#pragma unroll
  for (int p = 0; p < 8; ++p) {
    const s16x4 av = *(const s16x4*)(AO + p * P + base);
    s16x4 o;
#pragma unroll
    for (int e = 0; e < 4; ++e) {
      v[e][p] += b2f(av[e]);
      o[e] = f2b(v[e][p]);
      ss[e] += v[e][p] * v[e][p];
    }
    *(s16x4*)(X + p * P + base) = o;
  }
#pragma unroll
  for (int e = 0; e < 4; ++e) part += sqrtf(ss[e]);
#pragma unroll
  for (int off = 1; off < 32; off <<= 1) part += __shfl_xor(part, off);
  if ((tid & 31) == 0) nminv[base >> 7] = 1.f / (part / 128.f + EPSV);
}

// ---------------- GP elementwise (4-wide, in place over XL) -----------------
__global__ __launch_bounds__(256) void gp_kernel(
    bf16* __restrict__ XL, const bf16* __restrict__ XR)
{
  const size_t base = ((size_t)blockIdx.x * 256 + threadIdx.x) * 4;
  const size_t P = (size_t)NROWS * 256;
  s16x4 av[8], bv[8], rv[8];
#pragma unroll
  for (int p = 0; p < 8; ++p) {
    av[p] = *(const s16x4*)(XL + p * P + base);
    bv[p] = *(const s16x4*)(XR + p * P + base);
  }
#pragma unroll
  for (int e = 0; e < 4; ++e) {
    float a[8], b[8], r[8] = {0.f,0.f,0.f,0.f,0.f,0.f,0.f,0.f};
#pragma unroll
    for (int p = 0; p < 8; ++p) { a[p] = b2f(av[p][e]); b[p] = b2f(bv[p][e]); }
    gprod(a, b, r);
#pragma unroll
    for (int p = 0; p < 8; ++p) rv[p][e] = f2b(r[p]);
  }
#pragma unroll
  for (int p = 0; p < 8; ++p) *(s16x4*)(XL + p * P + base) = rv[p];
}

// ---- x3 = ln2a*Xres/nm2 + gna*Gl/nmg (4-wide, shfl norms, in place) --------
__global__ __launch_bounds__(256) void combine_kernel(
    bf16* __restrict__ X, const bf16* __restrict__ Gl,
    const float* __restrict__ ln2a, const float* __restrict__ gna,
    const float* __restrict__ nm2inv, float* __restrict__ nm4inv)
{
  const int tid = threadIdx.x;
  const size_t base = ((size_t)blockIdx.x * 256 + tid) * 4;
  const size_t P = (size_t)NROWS * 128;
  const size_t n = base >> 7;
  const int c = (int)(base & 127);

  float gv[4][8];
  float ssg[4] = {0.f,0.f,0.f,0.f};
#pragma unroll
  for (int p = 0; p < 8; ++p) {
    const s16x4 g4 = *(const s16x4*)(Gl + p * P + base);
#pragma unroll
    for (int e = 0; e < 4; ++e) { gv[e][p] = b2f(g4[e]); ssg[e] += gv[e][p] * gv[e][p]; }
  }
  float partg = sqrtf(ssg[0]) + sqrtf(ssg[1]) + sqrtf(ssg[2]) + sqrtf(ssg[3]);
#pragma unroll
  for (int off = 1; off < 32; off <<= 1) partg += __shfl_xor(partg, off);
  const float invg = 1.f / (partg / 128.f + EPSV);

  const float n2 = nm2inv[n];
  float s2[4], sg[4];
#pragma unroll
  for (int e = 0; e < 4; ++e) { s2[e] = ln2a[c + e] * n2; sg[e] = gna[c + e] * invg; }

  float ss[4] = {0.f,0.f,0.f,0.f};
#pragma unroll
  for (int p = 0; p < 8; ++p) {
    const s16x4 x4 = *(const s16x4*)(X + p * P + base);
    s16x4 o;
#pragma unroll
    for (int e = 0; e < 4; ++e) {
      const float v = s2[e] * b2f(x4[e]) + sg[e] * gv[e][p];
      o[e] = f2b(v);
      ss[e] += v * v;
    }
    *(s16x4*)(X + p * P + base) = o;
  }
  float part = sqrtf(ss[0]) + sqrtf(ss[1]) + sqrtf(ss[2]) + sqrtf(ss[3]);
#pragma unroll
  for (int off = 1; off < 32; off <<= 1) part += __shfl_xor(part, off);
  if ((tid & 31) == 0) nm4inv[n] = 1.f / (part / 128.f + EPSV);
}

// ---------------- MVSiLU (4-wide, in place) ---------------------------------
__global__ __launch_bounds__(256) void silu_kernel(
    bf16* __restrict__ H, const float* __restrict__ sa, const float* __restrict__ sb)
{
  const size_t base = ((size_t)blockIdx.x * 256 + threadIdx.x) * 4;
  const int c = (int)(base & 255);
  const size_t P = (size_t)NROWS * 256;
  s16x4 hv[8];
#pragma unroll
  for (int p = 0; p < 8; ++p) hv[p] = *(const s16x4*)(H + p * P + base);
#pragma unroll
  for (int e = 0; e < 4; ++e) {
    float v[8];
#pragma unroll
    for (int p = 0; p < 8; ++p) v[p] = b2f(hv[p][e]);
    const float i0 = v[0];
    const float i1 = v[1]*v[1] + v[2]*v[2] + v[3]*v[3];
    const float i2 = v[4]*v[4] + v[5]*v[5] + v[6]*v[6];
    const float i3 = v[7]*v[7];
    const int cc = c + e;
    const float g0 = 1.f / (1.f + __expf(-(sa[cc*4+0]*i0 + sb[cc*4+0])));
    const float g1 = 1.f / (1.f + __expf(-(sa[cc*4+1]*i1 + sb[cc*4+1])));
    const float g2 = 1.f / (1.f + __expf(-(sa[cc*4+2]*i2 + sb[cc*4+2])));
    const float g3 = 1.f / (1.f + __expf(-(sa[cc*4+3]*i3 + sb[cc*4+3])));
    v[0]*=g0; v[1]*=g1; v[2]*=g1; v[3]*=g1; v[4]*=g2; v[5]*=g2; v[6]*=g2; v[7]*=g3;
#pragma unroll
    for (int p = 0; p < 8; ++p) hv[p][e] = f2b(v[p]);
  }
#pragma unroll
  for (int p = 0; p < 8; ++p) *(s16x4*)(H + p * P + base) = hv[p];
}

// ---------------- launch ----------------------------------------------------
extern "C" void kernel_launch(void* const* d_in, const int* in_sizes, int n_in,
                              void* d_out, int out_size, void* d_ws, size_t ws_size,
                              hipStream_t stream) {
  (void)in_sizes; (void)n_in; (void)out_size; (void)ws_size;
  const float* src   = (const float*)d_in[0];
  const float* ln1_a = (const float*)d_in[1];
  const float* ln2_a = (const float*)d_in[2];
  const float* ln3_a = (const float*)d_in[3];
  const float* wq = (const float*)d_in[4];  const float* bq = (const float*)d_in[5];
  const float* wk = (const float*)d_in[6];  const float* bk = (const float*)d_in[7];
  const float* wv = (const float*)d_in[8];  const float* bv = (const float*)d_in[9];
  const float* wo = (const float*)d_in[10]; const float* bo = (const float*)d_in[11];
  const float* gw1 = (const float*)d_in[12]; const float* gb1 = (const float*)d_in[13];
  const float* gw2 = (const float*)d_in[14]; const float* gb2 = (const float*)d_in[15];
  const float* gw3 = (const float*)d_in[16]; const float* gb3 = (const float*)d_in[17];
  const float* gna = (const float*)d_in[18];
  const float* mw1 = (const float*)d_in[19]; const float* mb1 = (const float*)d_in[20];
  const float* sa  = (const float*)d_in[21]; const float* sb  = (const float*)d_in[22];
  const float* mw2 = (const float*)d_in[23]; const float* mb2 = (const float*)d_in[24];

  char* ws = (char*)d_ws;
  const size_t HALF = 52428800; // 52.4 MB = one [8][N][128] bf16 plane-set

  // ws regions (by lifetime):
  bf16* Xp   = (bf16*)ws;                // [0,52.4): Xp -> Xres -> X3
  bf16* Qb   = (bf16*)(ws + HALF);       // [52.4,104.8): Q/O
  bf16* XLH  = (bf16*)(ws + HALF);       // [52.4,157.2): XL, later H  ([8][N][256])
  // weights
  bf16* WQKV = (bf16*)(ws + 157286400);                 // [4][384][128]
  bf16* WO   = WQKV + 196608;                           // [4][128][128]
  bf16* WG12 = WO   + 65536;                            // [4][512][128]
  bf16* WG3  = WG12 + 262144;                           // [4][128][256]
  bf16* WM1  = WG3  + 131072;                           // [4][256][128]
  bf16* WM2  = WM1  + 131072;                           // [4][128][256]
  float* BQKV = (float*)(ws + 159121408);               // 384
  float* BG12 = BQKV + 384;                             // 512
  float* nm1  = BG12 + 512;
  float* nm2  = nm1 + NROWS;
  float* nm4  = nm2 + NROWS;

  // d_out regions (scratch until the final fused epilogue):
  bf16* Kb = (bf16*)d_out;                     // [0,52.4): K -> AO -> (XR lo) -> Gl
  bf16* Vb = (bf16*)d_out + HALF / 2;          // [52.4,104.8): V -> (XR hi)
  bf16* AO = (bf16*)d_out;                     // after attn
  bf16* XR = (bf16*)d_out;                     // [8][N][256] over all of d_out
  bf16* Gl = (bf16*)d_out;                     // after gp/gw3

  wprep_all_kernel<<<896, 256, 0, stream>>>(
      wq, wk, wv, wo, gw1, gw2, gw3, mw1, mw2, ln1_a, ln2_a, ln3_a,
      WQKV, WO, WG12, WG3, WM1, WM2);
  bias_prep_kernel<<<4, 256, 0, stream>>>(bq, bk, bv, gb1, gb2, BQKV, BG12);

  repack_kernel<<<3200, 256, 0, stream>>>(src, Xp, nm1);

  GemmArgs P{};
  // QKV: A=Xp, W=WQKV, out {Q,K,V}
  P = GemmArgs{Xp, WQKV, BQKV, nm1, Qb, Kb, Vb, nullptr, 0,0,0,0, 384, 128,
               nullptr, nullptr, nullptr, nullptr};
  gemm2_kernel<128, 128, false><<<dim3(200, 3, 2), 256, 0, stream>>>(P);

  attn_kernel<<<2048, 256, 0, stream>>>(Qb, Kb, Vb);

  // WO: A=O(Qb) -> AO
  P = GemmArgs{Qb, WO, bo, nullptr, AO, nullptr, nullptr, nullptr, 0,0,0,0, 128, 128,
               nullptr, nullptr, nullptr, nullptr};
  gemm2_kernel<128, 128, false><<<dim3(200, 1, 2), 256, 0, stream>>>(P);

  xres_kernel<<<3200, 256, 0, stream>>>(src, AO, Xp, nm2);

  // GW12: A=Xres -> XL (ws) cols 0-255, XR (d_out) cols 256-511
  P = GemmArgs{Xp, WG12, BG12, nm2, XLH, XLH, XR, XR, 0, 128, 0, 128, 512, 256,
               nullptr, nullptr, nullptr, nullptr};
  gemm2_kernel<128, 128, false><<<dim3(200, 4, 2), 256, 0, stream>>>(P);

  gp_kernel<<<6400, 256, 0, stream>>>(XLH, XR);

  // GW3: A=GP(XLH, 256-wide) -> Gl (d_out)
  P = GemmArgs{XLH, WG3, gb3, nullptr, Gl, nullptr, nullptr, nullptr, 0,0,0,0, 128, 128,
               nullptr, nullptr, nullptr, nullptr};
  gemm2_kernel<256, 256, false><<<dim3(200, 1, 2), 256, 0, stream>>>(P);

  combine_kernel<<<3200, 256, 0, stream>>>(Xp, Gl, ln2_a, gna, nm2, nm4);

  // MW1: A=X3 -> H (ws, 256-wide)
  P = GemmArgs{Xp, WM1, mb1, nm4, XLH, XLH, nullptr, nullptr, 0, 128, 0, 0, 256, 256,
               nullptr, nullptr, nullptr, nullptr};
  gemm2_kernel<128, 128, false><<<dim3(200, 2, 2), 256, 0, stream>>>(P);

  silu_kernel<<<6400, 256, 0, stream>>>(XLH, sa, sb);

  // MW2 + fused final: A=H -> out = acc + ln3a*X3/nm4 (fp32 interleaved)
  P = GemmArgs{XLH, WM2, mb2, nullptr, nullptr, nullptr, nullptr, nullptr, 0,0,0,0, 128, 128,
               Xp, ln3_a, nm4, (float*)d_out};
  gemm2_kernel<256, 256, true><<<dim3(200, 1, 2), 256, 0, stream>>>(P);
}

// Round 6
// 664.578 us; speedup vs baseline: 1.3182x; 1.3182x over previous
//
#include <hip/hip_runtime.h>
#include <hip/hip_bf16.h>
#include <math.h>

#define NROWS 25600
#define SEQL  25
#define EPSV  1e-6f

typedef __hip_bfloat16 bf16;
typedef __attribute__((ext_vector_type(4))) float f32x4;
typedef __attribute__((ext_vector_type(8))) short bf16x8;
typedef __attribute__((ext_vector_type(4))) short s16x4;
typedef unsigned int u32;

#define GLD16(gp_, lp_) __builtin_amdgcn_global_load_lds( \
    (const __attribute__((address_space(1))) u32*)(gp_), \
    (__attribute__((address_space(3))) u32*)(lp_), 16, 0, 0)

__device__ __forceinline__ float b2f(short s) {
  return __uint_as_float(((u32)(unsigned short)s) << 16);
}
__device__ __forceinline__ short f2b(float f) {
  __hip_bfloat16 h = __float2bfloat16(f);
  return *reinterpret_cast<short*>(&h);
}

// ---------------- Cl(3,0) geometric product (fp32) --------------------------
__device__ __forceinline__ void gprod(const float* a, const float* b, float* r) {
  const int M[8] = {0,1,2,4,3,5,6,7};
  const int P[8] = {0,1,2,4,3,5,6,7};
#pragma unroll
  for (int i = 0; i < 8; ++i) {
    const int ma = M[i];
#pragma unroll
    for (int k = 0; k < 8; ++k) {
      const int mb = M[k];
      int par = 0;
      for (int t = ma >> 1; t; t >>= 1) par += __popc(t & mb);
      const float s = (par & 1) ? -1.f : 1.f;
      r[P[ma ^ mb]] += s * a[i] * b[k];
    }
  }
}

// ---------------- MFMA GEMM with XOR-swizzled LDS (round-3, proven) ---------
template<int KT, int ON>
__global__ __launch_bounds__(256) void gemm_kernel(
    const bf16* __restrict__ A, const bf16* __restrict__ W,
    const float* __restrict__ bias, const float* __restrict__ invnm,
    bf16* __restrict__ Y)
{
  __shared__ __align__(16) short As[128 * 128];
  __shared__ __align__(16) short Bs[128 * 128];
  const int tid  = threadIdx.x;
  const int lane = tid & 63;
  const int wid  = tid >> 6;
  const int pl   = blockIdx.z;
  const int g    = (pl == 0) ? 0 : ((pl < 4) ? 1 : ((pl < 7) ? 2 : 3));
  const size_t n0 = (size_t)blockIdx.x * 128;
  const int c0    = blockIdx.y * 128;
  const bf16* Ab = A + (size_t)pl * NROWS * KT + n0 * KT;
  const bf16* Wb = W + ((size_t)g * ON + c0) * KT;

  f32x4 acc[4][4];
#pragma unroll
  for (int i = 0; i < 4; ++i)
#pragma unroll
    for (int j = 0; j < 4; ++j) acc[i][j] = (f32x4){0.f, 0.f, 0.f, 0.f};

  const int wm = (wid & 1) * 64;
  const int wn = (wid >> 1) * 64;
  const int lg  = lane >> 4;
  const int c8  = lane & 15;
  const int l15 = lane & 15;

  constexpr int NC = KT / 128;
#pragma unroll
  for (int kc = 0; kc < NC; ++kc) {
#pragma unroll
    for (int j = 0; j < 8; ++j) {
      const int row = wid * 32 + j * 4 + lg;
      const int sw = (c8 ^ (row & 7)) * 8;
      const bf16* ga = Ab + (size_t)row * KT + kc * 128 + sw;
      const bf16* gb = Wb + (size_t)row * KT + kc * 128 + sw;
      GLD16(ga, &As[wid * 4096 + j * 512]);
      GLD16(gb, &Bs[wid * 4096 + j * 512]);
    }
    __syncthreads();
#pragma unroll
    for (int ks = 0; ks < 4; ++ks) {
      bf16x8 af[4], bg[4];
#pragma unroll
      for (int i = 0; i < 4; ++i) {
        const int rA = wm + i * 16 + l15;
        const int rB = wn + i * 16 + l15;
        af[i] = *(const bf16x8*)&As[rA * 128 + (((ks * 4 + lg) ^ (rA & 7)) * 8)];
        bg[i] = *(const bf16x8*)&Bs[rB * 128 + (((ks * 4 + lg) ^ (rB & 7)) * 8)];
      }
#pragma unroll
      for (int mi = 0; mi < 4; ++mi)
#pragma unroll
        for (int ni = 0; ni < 4; ++ni)
          acc[mi][ni] = __builtin_amdgcn_mfma_f32_16x16x32_bf16(af[mi], bg[ni], acc[mi][ni], 0, 0, 0);
    }
    if (kc + 1 < NC) __syncthreads();
  }

  const int cr = (lane >> 4) * 4;
  const int cc = lane & 15;
  bf16* Yb = Y + (size_t)pl * NROWS * ON;
#pragma unroll
  for (int mi = 0; mi < 4; ++mi) {
#pragma unroll
    for (int j = 0; j < 4; ++j) {
      const size_t n = n0 + wm + mi * 16 + cr + j;
      const float sc = invnm ? invnm[n] : 1.f;
#pragma unroll
      for (int ni = 0; ni < 4; ++ni) {
        const int colg = c0 + wn + ni * 16 + cc;
        float v = acc[mi][ni][j] * sc;
        if (pl == 0) v += bias[colg];
        Yb[n * ON + colg] = __float2bfloat16(v);
      }
    }
  }
}

// ---------------- weight prep: combined WQKV + separate others --------------
__global__ __launch_bounds__(256) void wprep_all_kernel(
    const float* wq, const float* wk, const float* wv, const float* wo,
    const float* gw1, const float* gw2, const float* gw3,
    const float* mw1, const float* mw2,
    const float* ln1, const float* ln2, const float* ln3,
    bf16* WQKV, bf16* WO, bf16* WG1, bf16* WG2, bf16* WG3, bf16* WM1, bf16* WM2)
{
  const int gid = blockIdx.x * 256 + threadIdx.x;
  const float* w; const float* ln; bf16* out; int K; int idx; int planeSz; int rowOfs;
  if      (gid <  16384) { w=wq;  ln=ln1;     out=WQKV; K=128; idx=gid;        planeSz=49152; rowOfs=0;   }
  else if (gid <  32768) { w=wk;  ln=ln1;     out=WQKV; K=128; idx=gid-16384;  planeSz=49152; rowOfs=128; }
  else if (gid <  49152) { w=wv;  ln=ln1;     out=WQKV; K=128; idx=gid-32768;  planeSz=49152; rowOfs=256; }
  else if (gid <  65536) { w=wo;  ln=nullptr; out=WO;   K=128; idx=gid-49152;  planeSz=16384; rowOfs=0;   }
  else if (gid <  98304) { w=gw1; ln=ln2;     out=WG1;  K=128; idx=gid-65536;  planeSz=32768; rowOfs=0;   }
  else if (gid < 131072) { w=gw2; ln=ln2;     out=WG2;  K=128; idx=gid-98304;  planeSz=32768; rowOfs=0;   }
  else if (gid < 163840) { w=gw3; ln=nullptr; out=WG3;  K=256; idx=gid-131072; planeSz=32768; rowOfs=0;   }
  else if (gid < 196608) { w=mw1; ln=ln3;     out=WM1;  K=128; idx=gid-163840; planeSz=32768; rowOfs=0;   }
  else                   { w=mw2; ln=nullptr; out=WM2;  K=256; idx=gid-196608; planeSz=32768; rowOfs=0;   }
  const int k = idx % K;
  const float s = ln ? ln[k] : 1.f;
  const float4 wv4 = *(const float4*)(w + (size_t)idx * 4);
  bf16* dst = out + (size_t)rowOfs * K + idx;
  dst[0 * planeSz] = __float2bfloat16(wv4.x * s);
  dst[1 * planeSz] = __float2bfloat16(wv4.y * s);
  dst[2 * planeSz] = __float2bfloat16(wv4.z * s);
  dst[3 * planeSz] = __float2bfloat16(wv4.w * s);
}

// ---------------- fused repack + QKV + attention ----------------------------
// 1 block per batch. Reads src fp32; writes O planar bf16 [8][NROWS][128].
// LN1 fold in WQKV (k-dim); 1/nm1 computed in-block, applied in epilogues.
__global__ __launch_bounds__(256) void attn_mega_kernel(
    const float* __restrict__ src, const bf16* __restrict__ WQKV,
    const float* __restrict__ bq, const float* __restrict__ bk,
    const float* __restrict__ bv, bf16* __restrict__ O)
{
  __shared__ __align__(16) short Xs[8 * 25 * 128];   // 51200 B, swizzled chunks
  __shared__ __align__(16) short QKs[4][2][32 * 128];// 65536 B (per-wave Q/K, V^T reuses Q)
  __shared__ __align__(16) short Ps[4][32 * 32];     // 8192 B  (per-wave P)
  __shared__ float redN[32];
  __shared__ float invnS[32];

  const int tid  = threadIdx.x;
  const int lane = tid & 63;
  const int wid  = tid >> 6;
  const int l15  = lane & 15;
  const int lg   = lane >> 4;
  const int b    = blockIdx.x;
  const int N0   = b * SEQL;
  const size_t PS = (size_t)NROWS * 128;

  if (tid < 32) redN[tid] = 0.f;
  __syncthreads();

  // ---- stage src -> X (bf16, swizzled) + row mean-norms ----
  for (int i = 0; i < 13; ++i) {
    const int q = tid + i * 256;
    if (q < SEQL * 128) {
      const int n = q >> 7;
      const int c = q & 127;
      const float* sp = src + ((size_t)(N0 + n) * 128 + c) * 8;
      const float4 a = *(const float4*)sp;
      const float4 bb = *(const float4*)(sp + 4);
      float v[8] = {a.x, a.y, a.z, a.w, bb.x, bb.y, bb.z, bb.w};
      float ss = 0.f;
#pragma unroll
      for (int p = 0; p < 8; ++p) ss += v[p] * v[p];
      float nrm = sqrtf(ss);
      const int colbase = (((c >> 3) ^ (n & 7)) * 8) + (c & 7);
#pragma unroll
      for (int p = 0; p < 8; ++p) Xs[p * 3200 + n * 128 + colbase] = f2b(v[p]);
#pragma unroll
      for (int off = 1; off < 64; off <<= 1) nrm += __shfl_xor(nrm, off);
      if (lane == 0) atomicAdd(&redN[n], nrm);  // all 64 lanes share n
    }
  }
  __syncthreads();
  if (tid < 32) invnS[tid] = (tid < SEQL) ? 1.f / (redN[tid] / 128.f + EPSV) : 0.f;
  __syncthreads();

  float inz[8];
#pragma unroll
  for (int si = 0; si < 2; ++si)
#pragma unroll
    for (int j = 0; j < 4; ++j) inz[si * 4 + j] = invnS[si * 16 + lg * 4 + j];
  const float inzT0 = invnS[l15];
  const float inzT1 = invnS[16 + l15];

  short* Qb = &QKs[wid][0][0];
  short* Kb = &QKs[wid][1][0];
  short* Pb = &Ps[wid][0];
  const int r0c = l15;                                   // tile-0 rows < 25
  const int r1c = (16 + l15 > 24) ? 24 : (16 + l15);     // clamp pad rows

  for (int hh = 0; hh < 2; ++hh) {
    const int h = wid * 2 + hh;

    // ---- Q and K GEMMs (per plane, M=32, N=16, K=128) ----
#pragma unroll
    for (int mat = 0; mat < 2; ++mat) {
      short* Ob = mat ? Kb : Qb;
      const float bia = (mat ? bk : bq)[h * 16 + l15];
      for (int p = 0; p < 8; ++p) {
        const int g = (p == 0) ? 0 : ((p < 4) ? 1 : ((p < 7) ? 2 : 3));
        const bf16* Wr = WQKV + ((size_t)g * 384 + mat * 128 + h * 16 + l15) * 128;
        f32x4 a0 = (f32x4){0.f,0.f,0.f,0.f}, a1 = (f32x4){0.f,0.f,0.f,0.f};
#pragma unroll
        for (int ks = 0; ks < 4; ++ks) {
          const bf16x8 wf = *(const bf16x8*)(Wr + ks * 32 + lg * 8);
          const int c16 = ks * 4 + lg;
          const bf16x8 x0 = *(const bf16x8*)&Xs[p * 3200 + r0c * 128 + ((c16 ^ (r0c & 7)) * 8)];
          const bf16x8 x1 = *(const bf16x8*)&Xs[p * 3200 + r1c * 128 + ((c16 ^ (r1c & 7)) * 8)];
          a0 = __builtin_amdgcn_mfma_f32_16x16x32_bf16(x0, wf, a0, 0, 0, 0);
          a1 = __builtin_amdgcn_mfma_f32_16x16x32_bf16(x1, wf, a1, 0, 0, 0);
        }
        const int fch = p * 2 + (l15 >> 3);  // chunk of f = p*16+l15
        const int fo  = l15 & 7;
#pragma unroll
        for (int j = 0; j < 4; ++j) {
          const int na = lg * 4 + j;
          const int nb = 16 + lg * 4 + j;
          const float v0 = a0[j] * inz[j]     + ((p == 0) ? bia : 0.f);
          const float v1 = a1[j] * inz[4 + j] + ((p == 0) ? bia : 0.f);
          Ob[na * 128 + ((fch ^ (na & 7)) * 8) + fo] = f2b(v0);
          Ob[nb * 128 + ((fch ^ (nb & 7)) * 8) + fo] = f2b(v1);
        }
      }
    }

    // ---- S = Q K^T over 128 feats ----
    f32x4 sacc[2][2];
#pragma unroll
    for (int si = 0; si < 2; ++si)
#pragma unroll
      for (int ti = 0; ti < 2; ++ti) sacc[si][ti] = (f32x4){0.f,0.f,0.f,0.f};
#pragma unroll
    for (int ks = 0; ks < 4; ++ks) {
      const int c16 = ks * 4 + lg;
      const int ra = l15, rb = 16 + l15;
      const bf16x8 qa0 = *(const bf16x8*)&Qb[ra * 128 + ((c16 ^ (ra & 7)) * 8)];
      const bf16x8 qa1 = *(const bf16x8*)&Qb[rb * 128 + ((c16 ^ (rb & 7)) * 8)];
      const bf16x8 kb0 = *(const bf16x8*)&Kb[ra * 128 + ((c16 ^ (ra & 7)) * 8)];
      const bf16x8 kb1 = *(const bf16x8*)&Kb[rb * 128 + ((c16 ^ (rb & 7)) * 8)];
      sacc[0][0] = __builtin_amdgcn_mfma_f32_16x16x32_bf16(qa0, kb0, sacc[0][0], 0, 0, 0);
      sacc[0][1] = __builtin_amdgcn_mfma_f32_16x16x32_bf16(qa0, kb1, sacc[0][1], 0, 0, 0);
      sacc[1][0] = __builtin_amdgcn_mfma_f32_16x16x32_bf16(qa1, kb0, sacc[1][0], 0, 0, 0);
      sacc[1][1] = __builtin_amdgcn_mfma_f32_16x16x32_bf16(qa1, kb1, sacc[1][1], 0, 0, 0);
    }

    // ---- softmax over t (16-lane group reduce; round-3 verified) ----
    const float scale = 0.08838834764831845f;
    float pv[2][2][4];
#pragma unroll
    for (int si = 0; si < 2; ++si)
#pragma unroll
      for (int ti = 0; ti < 2; ++ti)
#pragma unroll
        for (int r = 0; r < 4; ++r) {
          float v = sacc[si][ti][r] * scale;
          if (ti * 16 + l15 > 24) v = -1e30f;
          pv[si][ti][r] = v;
        }
#pragma unroll
    for (int si = 0; si < 2; ++si)
#pragma unroll
      for (int r = 0; r < 4; ++r) {
        float m = fmaxf(pv[si][0][r], pv[si][1][r]);
#pragma unroll
        for (int off = 1; off < 16; off <<= 1) m = fmaxf(m, __shfl_xor(m, off));
        const float e0 = __expf(pv[si][0][r] - m);
        const float e1 = __expf(pv[si][1][r] - m);
        float sum = e0 + e1;
#pragma unroll
        for (int off = 1; off < 16; off <<= 1) sum += __shfl_xor(sum, off);
        const float inv = 1.f / sum;
        pv[si][0][r] = e0 * inv;
        pv[si][1][r] = e1 * inv;
      }

    // ---- P -> LDS [32n][32t], 4-chunk XOR swizzle ----
#pragma unroll
    for (int si = 0; si < 2; ++si)
#pragma unroll
      for (int ti = 0; ti < 2; ++ti)
#pragma unroll
        for (int r = 0; r < 4; ++r) {
          const int n = si * 16 + lg * 4 + r;
          const int t = ti * 16 + l15;
          Pb[n * 32 + (((t >> 3) ^ (n & 3)) * 8) + (t & 7)] = f2b(pv[si][ti][r]);
        }

    // ---- V^T (over Q's slot): Vt[f][t], f = p*16+d ----
    short* Vt = Qb;
    float bvj[4];
#pragma unroll
    for (int j = 0; j < 4; ++j) bvj[j] = bv[h * 16 + lg * 4 + j];
    for (int p = 0; p < 8; ++p) {
      const int g = (p == 0) ? 0 : ((p < 4) ? 1 : ((p < 7) ? 2 : 3));
      const bf16* Wr = WQKV + ((size_t)g * 384 + 256 + h * 16 + l15) * 128;
      f32x4 v0 = (f32x4){0.f,0.f,0.f,0.f}, v1 = (f32x4){0.f,0.f,0.f,0.f};
#pragma unroll
      for (int ks = 0; ks < 4; ++ks) {
        const bf16x8 wf = *(const bf16x8*)(Wr + ks * 32 + lg * 8);
        const int c16 = ks * 4 + lg;
        const bf16x8 x0 = *(const bf16x8*)&Xs[p * 3200 + r0c * 128 + ((c16 ^ (r0c & 7)) * 8)];
        const bf16x8 x1 = *(const bf16x8*)&Xs[p * 3200 + r1c * 128 + ((c16 ^ (r1c & 7)) * 8)];
        v0 = __builtin_amdgcn_mfma_f32_16x16x32_bf16(wf, x0, v0, 0, 0, 0);
        v1 = __builtin_amdgcn_mfma_f32_16x16x32_bf16(wf, x1, v1, 0, 0, 0);
      }
      // D[d][t]: lane col t = l15 (+16*ti), rows d = lg*4+j
#pragma unroll
      for (int j = 0; j < 4; ++j) {
        const int f = p * 16 + lg * 4 + j;
        const float vv0 = v0[j] * inzT0 + ((p == 0) ? bvj[j] : 0.f);
        const float vv1 = v1[j] * inzT1 + ((p == 0) ? bvj[j] : 0.f);
        const int t0 = l15, t1 = 16 + l15;
        Vt[f * 32 + (((t0 >> 3) ^ (f & 3)) * 8) + (t0 & 7)] = f2b(vv0);
        Vt[f * 32 + (((t1 >> 3) ^ (f & 3)) * 8) + (t1 & 7)] = f2b(vv1);
      }
    }

    // ---- O = P V : K=32 over t, one mfma per (n-tile, f-tile) ----
    const bf16x8 pa0 = *(const bf16x8*)&Pb[l15 * 32 + ((lg ^ (l15 & 3)) * 8)];
    const bf16x8 pa1 = *(const bf16x8*)&Pb[(16 + l15) * 32 + ((lg ^ ((16 + l15) & 3)) * 8)];
    f32x4 oacc[2][8];
#pragma unroll
    for (int si = 0; si < 2; ++si)
#pragma unroll
      for (int fi = 0; fi < 8; ++fi) oacc[si][fi] = (f32x4){0.f,0.f,0.f,0.f};
#pragma unroll
    for (int fi = 0; fi < 8; ++fi) {
      const int f = fi * 16 + l15;
      const bf16x8 vb = *(const bf16x8*)&Vt[f * 32 + ((lg ^ (f & 3)) * 8)];
      oacc[0][fi] = __builtin_amdgcn_mfma_f32_16x16x32_bf16(pa0, vb, oacc[0][fi], 0, 0, 0);
      oacc[1][fi] = __builtin_amdgcn_mfma_f32_16x16x32_bf16(pa1, vb, oacc[1][fi], 0, 0, 0);
    }

    // ---- write O planar: O[p=fi][N0+n][h*16+d=l15] ----
#pragma unroll
    for (int si = 0; si < 2; ++si)
#pragma unroll
      for (int fi = 0; fi < 8; ++fi)
#pragma unroll
        for (int j = 0; j < 4; ++j) {
          const int n = si * 16 + lg * 4 + j;
          if (n < SEQL)
            O[(size_t)fi * PS + (size_t)(N0 + n) * 128 + h * 16 + l15] =
                __float2bfloat16(oacc[si][fi][j]);
        }
  }
}

// ---------------- xres = src + AO (4-wide) + 1/nm2 --------------------------
__global__ __launch_bounds__(256) void xres_kernel(
    const float* __restrict__ src, const bf16* __restrict__ AO,
    bf16* __restrict__ X, float* __restrict__ nminv)
{
  const int tid = threadIdx.x;
  const size_t base = ((size_t)blockIdx.x * 256 + tid) * 4;
  const size_t P = (size_t)NROWS * 128;
  float v[4][8];
  const float4* sp = (const float4*)(src + base * 8);
#pragma unroll
  for (int e = 0; e < 4; ++e) {
    const float4 a = sp[e * 2], b = sp[e * 2 + 1];
    v[e][0]=a.x; v[e][1]=a.y; v[e][2]=a.z; v[e][3]=a.w;
    v[e][4]=b.x; v[e][5]=b.y; v[e][6]=b.z; v[e][7]=b.w;
  }
  float part = 0.f;
  float ss[4] = {0.f, 0.f, 0.f, 0.f};
#pragma unroll
  for (int p = 0; p < 8; ++p) {
    const s16x4 av = *(const s16x4*)(AO + p * P + base);
    s16x4 o;
#pragma unroll
    for (int e = 0; e < 4; ++e) {
      v[e][p] += b2f(av[e]);
      o[e] = f2b(v[e][p]);
      ss[e] += v[e][p] * v[e][p];
    }
    *(s16x4*)(X + p * P + base) = o;
  }
#pragma unroll
  for (int e = 0; e < 4; ++e) part += sqrtf(ss[e]);
#pragma unroll
  for (int off = 1; off < 32; off <<= 1) part += __shfl_xor(part, off);
  if ((tid & 31) == 0) nminv[base >> 7] = 1.f / (part / 128.f + EPSV);
}

// ---------------- GP elementwise (4-wide, in place over XL) -----------------
__global__ __launch_bounds__(256) void gp_kernel(
    bf16* __restrict__ XL, const bf16* __restrict__ XR)
{
  const size_t base = ((size_t)blockIdx.x * 256 + threadIdx.x) * 4;
  const size_t P = (size_t)NROWS * 256;
  s16x4 av[8], bv[8], rv[8];
#pragma unroll
  for (int p = 0; p < 8; ++p) {
    av[p] = *(const s16x4*)(XL + p * P + base);
    bv[p] = *(const s16x4*)(XR + p * P + base);
  }
#pragma unroll
  for (int e = 0; e < 4; ++e) {
    float a[8], b[8], r[8] = {0.f,0.f,0.f,0.f,0.f,0.f,0.f,0.f};
#pragma unroll
    for (int p = 0; p < 8; ++p) { a[p] = b2f(av[p][e]); b[p] = b2f(bv[p][e]); }
    gprod(a, b, r);
#pragma unroll
    for (int p = 0; p < 8; ++p) rv[p][e] = f2b(r[p]);
  }
#pragma unroll
  for (int p = 0; p < 8; ++p) *(s16x4*)(XL + p * P + base) = rv[p];
}

// ---- x3 = ln2a*Xres/nm2 + gna*Gl/nmg (4-wide, shfl norms, in place) --------
__global__ __launch_bounds__(256) void combine_kernel(
    bf16* __restrict__ X, const bf16* __restrict__ Gl,
    const float* __restrict__ ln2a, const float* __restrict__ gna,
    const float* __restrict__ nm2inv, float* __restrict__ nm4inv)
{
  const int tid = threadIdx.x;
  const size_t base = ((size_t)blockIdx.x * 256 + tid) * 4;
  const size_t P = (size_t)NROWS * 128;
  const size_t n = base >> 7;
  const int c = (int)(base & 127);

  float gv[4][8];
  float ssg[4] = {0.f,0.f,0.f,0.f};
#pragma unroll
  for (int p = 0; p < 8; ++p) {
    const s16x4 g4 = *(const s16x4*)(Gl + p * P + base);
#pragma unroll
    for (int e = 0; e < 4; ++e) { gv[e][p] = b2f(g4[e]); ssg[e] += gv[e][p] * gv[e][p]; }
  }
  float partg = sqrtf(ssg[0]) + sqrtf(ssg[1]) + sqrtf(ssg[2]) + sqrtf(ssg[3]);
#pragma unroll
  for (int off = 1; off < 32; off <<= 1) partg += __shfl_xor(partg, off);
  const float invg = 1.f / (partg / 128.f + EPSV);

  const float n2 = nm2inv[n];
  float s2[4], sg[4];
#pragma unroll
  for (int e = 0; e < 4; ++e) { s2[e] = ln2a[c + e] * n2; sg[e] = gna[c + e] * invg; }

  float ss[4] = {0.f,0.f,0.f,0.f};
#pragma unroll
  for (int p = 0; p < 8; ++p) {
    const s16x4 x4 = *(const s16x4*)(X + p * P + base);
    s16x4 o;
#pragma unroll
    for (int e = 0; e < 4; ++e) {
      const float v = s2[e] * b2f(x4[e]) + sg[e] * gv[e][p];
      o[e] = f2b(v);
      ss[e] += v * v;
    }
    *(s16x4*)(X + p * P + base) = o;
  }
  float part = sqrtf(ss[0]) + sqrtf(ss[1]) + sqrtf(ss[2]) + sqrtf(ss[3]);
#pragma unroll
  for (int off = 1; off < 32; off <<= 1) part += __shfl_xor(part, off);
  if ((tid & 31) == 0) nm4inv[n] = 1.f / (part / 128.f + EPSV);
}

// ---------------- MVSiLU (4-wide, in place) ---------------------------------
__global__ __launch_bounds__(256) void silu_kernel(
    bf16* __restrict__ H, const float* __restrict__ sa, const float* __restrict__ sb)
{
  const size_t base = ((size_t)blockIdx.x * 256 + threadIdx.x) * 4;
  const int c = (int)(base & 255);
  const size_t P = (size_t)NROWS * 256;
  s16x4 hv[8];
#pragma unroll
  for (int p = 0; p < 8; ++p) hv[p] = *(const s16x4*)(H + p * P + base);
#pragma unroll
  for (int e = 0; e < 4; ++e) {
    float v[8];
#pragma unroll
    for (int p = 0; p < 8; ++p) v[p] = b2f(hv[p][e]);
    const float i0 = v[0];
    const float i1 = v[1]*v[1] + v[2]*v[2] + v[3]*v[3];
    const float i2 = v[4]*v[4] + v[5]*v[5] + v[6]*v[6];
    const float i3 = v[7]*v[7];
    const int cc = c + e;
    const float g0 = 1.f / (1.f + __expf(-(sa[cc*4+0]*i0 + sb[cc*4+0])));
    const float g1 = 1.f / (1.f + __expf(-(sa[cc*4+1]*i1 + sb[cc*4+1])));
    const float g2 = 1.f / (1.f + __expf(-(sa[cc*4+2]*i2 + sb[cc*4+2])));
    const float g3 = 1.f / (1.f + __expf(-(sa[cc*4+3]*i3 + sb[cc*4+3])));
    v[0]*=g0; v[1]*=g1; v[2]*=g1; v[3]*=g1; v[4]*=g2; v[5]*=g2; v[6]*=g2; v[7]*=g3;
#pragma unroll
    for (int p = 0; p < 8; ++p) hv[p][e] = f2b(v[p]);
  }
#pragma unroll
  for (int p = 0; p < 8; ++p) *(s16x4*)(H + p * P + base) = hv[p];
}

// ---------------- final: out = ln3a*X3/nm4 + FF (4-wide, coalesced) ---------
__global__ __launch_bounds__(256) void final_kernel(
    const bf16* __restrict__ X3, const bf16* __restrict__ FF,
    const float* __restrict__ ln3a, const float* __restrict__ nm4inv,
    float* __restrict__ out)
{
  const size_t base = ((size_t)blockIdx.x * 256 + threadIdx.x) * 4;
  const int c = (int)(base & 127);
  const size_t n = base >> 7;
  const size_t P = (size_t)NROWS * 128;
  const float nm = nm4inv[n];
  float o[4][8];
#pragma unroll
  for (int p = 0; p < 8; ++p) {
    const s16x4 x4 = *(const s16x4*)(X3 + p * P + base);
    const s16x4 f4 = *(const s16x4*)(FF + p * P + base);
#pragma unroll
    for (int e = 0; e < 4; ++e)
      o[e][p] = ln3a[c + e] * nm * b2f(x4[e]) + b2f(f4[e]);
  }
  float4* op = (float4*)(out + base * 8);
#pragma unroll
  for (int e = 0; e < 4; ++e) {
    float4 lo, hi;
    lo.x=o[e][0]; lo.y=o[e][1]; lo.z=o[e][2]; lo.w=o[e][3];
    hi.x=o[e][4]; hi.y=o[e][5]; hi.z=o[e][6]; hi.w=o[e][7];
    op[e * 2] = lo;
    op[e * 2 + 1] = hi;
  }
}

// ---------------- launch ----------------------------------------------------
extern "C" void kernel_launch(void* const* d_in, const int* in_sizes, int n_in,
                              void* d_out, int out_size, void* d_ws, size_t ws_size,
                              hipStream_t stream) {
  (void)in_sizes; (void)n_in; (void)out_size; (void)ws_size;
  const float* src   = (const float*)d_in[0];
  const float* ln1_a = (const float*)d_in[1];
  const float* ln2_a = (const float*)d_in[2];
  const float* ln3_a = (const float*)d_in[3];
  const float* wq = (const float*)d_in[4];  const float* bq = (const float*)d_in[5];
  const float* wk = (const float*)d_in[6];  const float* bk = (const float*)d_in[7];
  const float* wv = (const float*)d_in[8];  const float* bv = (const float*)d_in[9];
  const float* wo = (const float*)d_in[10]; const float* bo = (const float*)d_in[11];
  const float* gw1 = (const float*)d_in[12]; const float* gb1 = (const float*)d_in[13];
  const float* gw2 = (const float*)d_in[14]; const float* gb2 = (const float*)d_in[15];
  const float* gw3 = (const float*)d_in[16]; const float* gb3 = (const float*)d_in[17];
  const float* gna = (const float*)d_in[18];
  const float* mw1 = (const float*)d_in[19]; const float* mb1 = (const float*)d_in[20];
  const float* sa  = (const float*)d_in[21]; const float* sb  = (const float*)d_in[22];
  const float* mw2 = (const float*)d_in[23]; const float* mb2 = (const float*)d_in[24];

  char* ws = (char*)d_ws;
  bf16* R1 = (bf16*)ws;                       // 104,857,600 B ([8][N][256] capable)
  bf16* R2 = (bf16*)(ws + 104857600);         //  52,428,800 B ([8][N][128])
  bf16* WQKV = (bf16*)(ws + 157286400);       // [4][384][128]
  bf16* WO  = WQKV + 196608;                  // [4][128][128]
  bf16* WG1 = WO   + 65536;                   // [4][256][128]
  bf16* WG2 = WG1  + 131072;                  // [4][256][128]
  bf16* WG3 = WG2  + 131072;                  // [4][128][256]
  bf16* WM1 = WG3  + 131072;                  // [4][256][128]
  bf16* WM2 = WM1  + 131072;                  // [4][128][256]
  float* nm2 = (float*)(ws + 159252480);
  float* nm4 = nm2 + NROWS;

  bf16* Dd = (bf16*)d_out;   // scratch: XL/GP/H ([8][N][256]); final fp32 out

  wprep_all_kernel<<<896, 256, 0, stream>>>(
      wq, wk, wv, wo, gw1, gw2, gw3, mw1, mw2, ln1_a, ln2_a, ln3_a,
      WQKV, WO, WG1, WG2, WG3, WM1, WM2);

  // fused repack+QKV+attn -> O planar in R2
  attn_mega_kernel<<<1024, 256, 0, stream>>>(src, WQKV, bq, bk, bv, R2);

  dim3 g128(NROWS / 128, 1, 8), g256(NROWS / 128, 2, 8);

  // AO = mv_linear(O, wo, bo) -> R1 (first 52.4MB)
  gemm_kernel<128, 128><<<g128, 256, 0, stream>>>(R2, WO, bo, nullptr, R1);

  // Xres = src + AO -> R2 (O dead) ; 1/nm2
  xres_kernel<<<3200, 256, 0, stream>>>(src, R1, R2, nm2);

  // XL = mv_linear(LN2(Xres), gw1) -> Dd ; XR -> R1 (full 104.8MB)
  gemm_kernel<128, 256><<<g256, 256, 0, stream>>>(R2, WG1, gb1, nm2, Dd);
  gemm_kernel<128, 256><<<g256, 256, 0, stream>>>(R2, WG2, gb2, nm2, R1);

  // GP in place over XL
  gp_kernel<<<6400, 256, 0, stream>>>(Dd, R1);

  // Gl = mv_linear(GP, gw3, gb3) -> R1 (first 52.4MB)
  gemm_kernel<256, 128><<<g128, 256, 0, stream>>>(Dd, WG3, gb3, nullptr, R1);

  // X3 = ln2a*Xres/nm2 + gna*Gl/nmg (in place in R2) ; 1/nm4
  combine_kernel<<<3200, 256, 0, stream>>>(R2, R1, ln2_a, gna, nm2, nm4);

  // H = mv_linear(LN3(X3), mw1, mb1) -> Dd
  gemm_kernel<128, 256><<<g256, 256, 0, stream>>>(R2, WM1, mb1, nm4, Dd);

  // MVSiLU in place on H
  silu_kernel<<<6400, 256, 0, stream>>>(Dd, sa, sb);

  // FF = mv_linear(H, mw2, mb2) -> R1 (first 52.4MB)
  gemm_kernel<256, 128><<<g128, 256, 0, stream>>>(Dd, WM2, mb2, nullptr, R1);

  // out = ln3a*X3/nm4 + FF -> d_out fp32 interleaved (coalesced)
  final_kernel<<<3200, 256, 0, stream>>>(R2, R1, ln3_a, nm4, (float*)d_out);
}